// Round 16
// baseline (198.121 us; speedup 1.0000x reference)
//
#include <hip/hip_runtime.h>
#include <hip/hip_bf16.h>
#include <stdint.h>

#define B_    4
#define S_    4096
#define STXT_ 77
#define C_    1280
#define CC_   768
#define H_    20
#define TIP_  4
#define D_    64
#define KVLD  2560

using short8 = __attribute__((ext_vector_type(8))) short;
using f32x4  = __attribute__((ext_vector_type(4))) float;

__device__ __forceinline__ ushort f2bf(float f) {
  union { float f; uint32_t u; } x; x.f = f;
  uint32_t r = (x.u + 0x7FFFu + ((x.u >> 16) & 1u)) >> 16;
  return (ushort)r;
}

__device__ __forceinline__ void gload_lds16(ushort* lds, const ushort* g) {
  __builtin_amdgcn_global_load_lds(
      (const __attribute__((address_space(1))) void*)g,
      (__attribute__((address_space(3))) void*)lds, 16, 0, 0);
}

// XOR-swizzle for bf16 [rows][64] LDS tiles (row stride 128B)
__device__ __forceinline__ int kswz(int row, int colByte) {
  return row * 128 + (colByte ^ ((row & 7) << 4));
}

// ---------------- fused prep kernel ----------------
#define PREP_CONV   2048
#define PREP_TW     7040
#define PREP_TOTAL  (PREP_CONV + PREP_TW + 1536)

__global__ __launch_bounds__(256)
void prep_all(const float* __restrict__ hid, const float* __restrict__ enc,
              const float* __restrict__ ipx, const float* __restrict__ region,
              const float* __restrict__ wq, const float* __restrict__ wk,
              const float* __restrict__ wv, const float* __restrict__ wkip,
              const float* __restrict__ wvip, const float* __restrict__ wout,
              ushort* __restrict__ hb, ushort* __restrict__ encb,
              ushort* __restrict__ ipb, ushort* __restrict__ wqT,
              ushort* __restrict__ wkvT, ushort* __restrict__ wkvipT,
              ushort* __restrict__ woutT, float* __restrict__ regionT) {
  __shared__ float t[32][33];
  const int bid = blockIdx.x;
  const int tid = threadIdx.x;

  if (bid < PREP_CONV) {
    const size_t N0 = (size_t)B_ * S_ * C_;
    const size_t N1 = (size_t)B_ * STXT_ * CC_;
    const size_t N2 = (size_t)B_ * TIP_ * CC_;
    const size_t TOT4 = (N0 + N1 + N2) / 4;
    for (size_t i4 = (size_t)bid * 256 + tid; i4 < TOT4; i4 += (size_t)PREP_CONV * 256) {
      size_t i = i4 * 4;
      const float* src; ushort* dst; size_t off;
      if (i < N0)            { src = hid; dst = hb;   off = i; }
      else if (i < N0 + N1)  { src = enc; dst = encb; off = i - N0; }
      else                   { src = ipx; dst = ipb;  off = i - N0 - N1; }
      float4 v = *(const float4*)&src[off];
      ushort4 w;
      w.x = f2bf(v.x); w.y = f2bf(v.y); w.z = f2bf(v.z); w.w = f2bf(v.w);
      *(ushort4*)&dst[off] = w;
    }
    return;
  }

  const int tx = tid & 31, ty = tid >> 5;

  if (bid < PREP_CONV + PREP_TW) {
    const int u = bid - PREP_CONV;
    const float* src; ushort* dst; int K, n0, k0;
    if (u < 1600)        { src = wq;   dst = wqT;   K = C_;  n0 = (u % 40) * 32;  k0 = (u / 40) * 32; }
    else if (u < 5440) {
      const int w = u - 1600, zi = w / 960, r = w % 960;
      K = CC_; n0 = (r % 40) * 32; k0 = (r / 40) * 32;
      switch (zi) {
        case 0:  src = wk;   dst = wkvT;                       break;
        case 1:  src = wv;   dst = wkvT + (size_t)C_ * CC_;    break;
        case 2:  src = wkip; dst = wkvipT;                     break;
        default: src = wvip; dst = wkvipT + (size_t)C_ * CC_;  break;
      }
    }
    else                 { const int w = u - 5440;
                           src = wout; dst = woutT; K = C_;  n0 = (w % 40) * 32;  k0 = (w / 40) * 32; }
#pragma unroll
    for (int r = 0; r < 4; ++r) {
      int kk = k0 + ty + r * 8;
      t[ty + r * 8][tx] = src[(size_t)kk * C_ + n0 + tx];
    }
    __syncthreads();
#pragma unroll
    for (int r = 0; r < 4; ++r) {
      int nn = n0 + ty + r * 8;
      dst[(size_t)nn * K + k0 + tx] = f2bf(t[tx][ty + r * 8]);
    }
    return;
  }

  {
    const int u = bid - PREP_CONV - PREP_TW;   // [0,1536): B_ * 3 * 128
    const int b = u / 384;
    const int r = u % 384;
    const int s0 = (r % 128) * 32;
    const int k0 = (r / 128) * 32;
#pragma unroll
    for (int rr = 0; rr < 4; ++rr) {
      int ss = s0 + ty + rr * 8;
      int kk = k0 + tx;
      t[ty + rr * 8][tx] = (kk < STXT_) ? region[((size_t)b * S_ + ss) * STXT_ + kk] : 0.f;
    }
    __syncthreads();
#pragma unroll
    for (int rr = 0; rr < 4; ++rr) {
      int kk = k0 + ty + rr * 8;
      if (kk < STXT_)
        regionT[((size_t)b * STXT_ + kk) * S_ + s0 + tx] = t[tx][ty + rr * 8];
    }
  }
}

// ------ fused big GEMM launch: blocks [0,256) = Q-proj 256x320 (R8 body);
//        blocks [256,296) = K/V + IP projections 128x256, K=768 ------
// Attention-side outputs (qb, kvb, ipkvb) are written HEAD-MAJOR:
//   qb[((b*H+h)*S + s)*64 + d],  kvb K half [((b*H+h)*77 + t)*64 + d],
//   V half offset by B*H*77*64;  ipkvb likewise with T=4.
__global__ __launch_bounds__(512, 2)
void gemm_fused(const ushort* __restrict__ hb, const ushort* __restrict__ wqT,
                ushort* __restrict__ qb, const ushort* __restrict__ encb,
                const ushort* __restrict__ wkvT, ushort* __restrict__ kvb,
                const ushort* __restrict__ ipb, const ushort* __restrict__ wkvipT,
                ushort* __restrict__ ipkvb) {
  __shared__ char lds[147456];
  const int tid = threadIdx.x, lane = tid & 63, wid = tid >> 6;
  const int fr = lane & 15, fk = lane >> 4;
  const int swzf = (fr & 7) << 4;
  const int c0b = (fk * 16) ^ swzf;
  const int c1b = (64 + fk * 16) ^ swzf;

  if (blockIdx.x < 256) {
    const int NT = C_ >> 6;                   // 20 K-tiles
    int wg = blockIdx.x;
    wg = (wg & 7) * 32 + (wg >> 3);           // XCD swizzle over 256 blocks
    const int tM = (wg / 4) * 256;
    const int tN = (wg % 4) * 320;
    const int wm = wid >> 2, wn = wid & 3;    // wave tile: rows wm*128, cols wn*80

    f32x4 acc[8][5];
#pragma unroll
    for (int m = 0; m < 8; ++m)
#pragma unroll
      for (int n = 0; n < 5; ++n) acc[m][n] = (f32x4){0.f, 0.f, 0.f, 0.f};

    auto stage1 = [&](int buf, int k0, int isB, int c) {
      char* dst = lds + buf * 73728 + (isB ? 32768 : 0);
      const ushort* src = isB ? wqT : hb;
      const int rbase = isB ? tN : tM;
      const int L = c * 8192 + tid * 16;
      const int row = L >> 7;
      const int colb = (L & 127) ^ ((row & 7) << 4);
      gload_lds16((ushort*)(dst + L), &src[(size_t)(rbase + row) * C_ + k0 + (colb >> 1)]);
    };
    auto stageAll = [&](int buf, int k0) {
      stage1(buf, k0, 1, 0); stage1(buf, k0, 1, 1); stage1(buf, k0, 1, 2);
      stage1(buf, k0, 1, 3); stage1(buf, k0, 1, 4);
      stage1(buf, k0, 0, 0); stage1(buf, k0, 0, 1);
      stage1(buf, k0, 0, 2); stage1(buf, k0, 0, 3);
    };
    auto rdA = [&](const char* base, int mo, int cb, short8* dst) {
#pragma unroll
      for (int m = 0; m < 4; ++m)
        dst[m] = *(const short8*)(base + (wm * 128 + (mo + m) * 16 + fr) * 128 + cb);
    };
    auto rdB = [&](const char* base, int cb, short8* dst) {
#pragma unroll
      for (int n = 0; n < 5; ++n)
        dst[n] = *(const short8*)(base + 32768 + (wn * 80 + n * 16 + fr) * 128 + cb);
    };

    stageAll(0, 0);
    __syncthreads();

    int cur = 0;
#pragma unroll 1
    for (int kt = 0; kt < NT; ++kt) {
      const int nxt = cur ^ 1;
      if (kt + 1 < NT) stageAll(nxt, (kt + 1) << 6);
      const char* Bb_ = lds + cur * 73728;

      short8 afA[4], afB[4], afC[4], afD[4], bf0[5], bf1[5];
      rdA(Bb_, 0, c0b, afA);
      rdB(Bb_, c0b, bf0);
#pragma unroll
      for (int m = 0; m < 4; ++m)
#pragma unroll
        for (int n = 0; n < 5; ++n)
          acc[m][n] = __builtin_amdgcn_mfma_f32_16x16x32_bf16(afA[m], bf0[n], acc[m][n], 0, 0, 0);
      rdA(Bb_, 4, c0b, afB);
#pragma unroll
      for (int m = 0; m < 4; ++m)
#pragma unroll
        for (int n = 0; n < 5; ++n)
          acc[m + 4][n] = __builtin_amdgcn_mfma_f32_16x16x32_bf16(afB[m], bf0[n], acc[m + 4][n], 0, 0, 0);
      rdA(Bb_, 0, c1b, afC);
      rdB(Bb_, c1b, bf1);
#pragma unroll
      for (int m = 0; m < 4; ++m)
#pragma unroll
        for (int n = 0; n < 5; ++n)
          acc[m][n] = __builtin_amdgcn_mfma_f32_16x16x32_bf16(afC[m], bf1[n], acc[m][n], 0, 0, 0);
      rdA(Bb_, 4, c1b, afD);
#pragma unroll
      for (int m = 0; m < 4; ++m)
#pragma unroll
        for (int n = 0; n < 5; ++n)
          acc[m + 4][n] = __builtin_amdgcn_mfma_f32_16x16x32_bf16(afD[m], bf1[n], acc[m + 4][n], 0, 0, 0);

      __syncthreads();
      cur = nxt;
    }

    // epilogue: head-major qb write, pre-scaled by 0.125
#pragma unroll
    for (int m = 0; m < 8; ++m) {
      const int grow = tM + wm * 128 + m * 16 + (lane >> 4) * 4;
      const int b = grow >> 12;
#pragma unroll
      for (int n = 0; n < 5; ++n) {
        const int col = tN + wn * 80 + n * 16 + fr;
        const int h = col >> 6, d = col & 63;
#pragma unroll
        for (int j = 0; j < 4; ++j) {
          const int s = (grow + j) & 4095;
          qb[(((size_t)b * H_ + h) * S_ + s) * D_ + d] = f2bf(acc[m][n][j] * 0.125f);
        }
      }
    }
    return;
  }

  // ---------------- K/V + IP projection path: 128x256, K=768, 12 tiles ----------------
  {
    int u = blockIdx.x - 256;                 // [0,40)
    const ushort* A; const ushort* Bt; ushort* Co; int M, T, tM, tN;
    if (u < 30) { A = encb; Bt = wkvT;   Co = kvb;   M = B_ * STXT_; T = STXT_;
                  tM = (u / 10) * 128; tN = (u % 10) * 256; }
    else        { u -= 30; A = ipb; Bt = wkvipT; Co = ipkvb; M = B_ * TIP_; T = TIP_;
                  tM = 0; tN = u * 256; }
    const size_t vOff = (size_t)B_ * H_ * T * D_;   // V half offset
    const int wm = wid >> 2, wn = wid & 3;    // rows wm*64, cols wn*64

    f32x4 acc[4][4];
#pragma unroll
    for (int m = 0; m < 4; ++m)
#pragma unroll
      for (int n = 0; n < 4; ++n) acc[m][n] = (f32x4){0.f, 0.f, 0.f, 0.f};

    auto stage1k = [&](int buf, int k0, int isB, int c) {
      char* dst = lds + buf * 49152 + (isB ? 16384 : 0);
      const ushort* src = isB ? Bt : A;
      const int L = c * 8192 + tid * 16;
      const int row = L >> 7;
      const int colb = (L & 127) ^ ((row & 7) << 4);
      int r = isB ? (tN + row) : min(tM + row, M - 1);
      gload_lds16((ushort*)(dst + L), &src[(size_t)r * CC_ + k0 + (colb >> 1)]);
    };
    auto stageAllk = [&](int buf, int k0) {
      stage1k(buf, k0, 1, 0); stage1k(buf, k0, 1, 1);
      stage1k(buf, k0, 1, 2); stage1k(buf, k0, 1, 3);
      stage1k(buf, k0, 0, 0); stage1k(buf, k0, 0, 1);
    };
    auto rdAk = [&](const char* base, int cb, short8* dst) {
#pragma unroll
      for (int m = 0; m < 4; ++m)
        dst[m] = *(const short8*)(base + (wm * 64 + m * 16 + fr) * 128 + cb);
    };
    auto rdBk = [&](const char* base, int cb, short8* dst) {
#pragma unroll
      for (int n = 0; n < 4; ++n)
        dst[n] = *(const short8*)(base + 16384 + (wn * 64 + n * 16 + fr) * 128 + cb);
    };

    stageAllk(0, 0);
    __syncthreads();

    int cur = 0;
#pragma unroll 1
    for (int kt = 0; kt < 12; ++kt) {
      const int nxt = cur ^ 1;
      if (kt + 1 < 12) stageAllk(nxt, (kt + 1) << 6);
      const char* base = lds + cur * 49152;

      short8 af0[4], af1[4], bk0[4], bk1[4];
      rdAk(base, c0b, af0);
      rdBk(base, c0b, bk0);
#pragma unroll
      for (int m = 0; m < 4; ++m)
#pragma unroll
        for (int n = 0; n < 4; ++n)
          acc[m][n] = __builtin_amdgcn_mfma_f32_16x16x32_bf16(af0[m], bk0[n], acc[m][n], 0, 0, 0);
      rdAk(base, c1b, af1);
      rdBk(base, c1b, bk1);
#pragma unroll
      for (int m = 0; m < 4; ++m)
#pragma unroll
        for (int n = 0; n < 4; ++n)
          acc[m][n] = __builtin_amdgcn_mfma_f32_16x16x32_bf16(af1[m], bk1[n], acc[m][n], 0, 0, 0);

      __syncthreads();
      cur = nxt;
    }

    // epilogue: head-major write (K cols <1280, V cols >=1280)
#pragma unroll
    for (int m = 0; m < 4; ++m) {
      const int rbase = tM + wm * 64 + m * 16 + (lane >> 4) * 4;
#pragma unroll
      for (int n = 0; n < 4; ++n) {
        const int col = tN + wn * 64 + n * 16 + fr;
        const int isV = col >= C_;
        const int cc = isV ? col - C_ : col;
        const int h = cc >> 6, d = cc & 63;
#pragma unroll
        for (int j = 0; j < 4; ++j) {
          int row = rbase + j;
          if (row < M) {
            const int b = row / T, t = row % T;
            Co[(isV ? vOff : 0) + (((size_t)b * H_ + h) * T + t) * D_ + d] =
                f2bf(acc[m][n][j]);
          }
        }
      }
    }
  }
}

// ------ out-proj GEMM: 256x320 tile, BK=64, 2-buffer, one barrier/K-tile ------
__global__ __launch_bounds__(512, 2)
void gemm11(const ushort* __restrict__ A, const ushort* __restrict__ Bt,
            float* __restrict__ Cout, const float* __restrict__ bias,
            int N, int K) {
  __shared__ char lds[147456];
  const int NT = K >> 6;
  int wg = blockIdx.x;
  wg = (wg & 7) * ((int)gridDim.x >> 3) + (wg >> 3);
  const int nTn = N / 320;
  const int tM = (wg / nTn) * 256;
  const int tN = (wg % nTn) * 320;

  const int tid = threadIdx.x, lane = tid & 63, wid = tid >> 6;
  const int wm = wid >> 2, wn = wid & 3;
  const int fr = lane & 15, fk = lane >> 4;
  const int swzf = (fr & 7) << 4;
  const int c0b = (fk * 16) ^ swzf;
  const int c1b = (64 + fk * 16) ^ swzf;

  f32x4 acc[8][5];
#pragma unroll
  for (int m = 0; m < 8; ++m)
#pragma unroll
    for (int n = 0; n < 5; ++n) acc[m][n] = (f32x4){0.f, 0.f, 0.f, 0.f};

  auto stage1 = [&](int buf, int k0, int isB, int c) {
    char* dst = lds + buf * 73728 + (isB ? 32768 : 0);
    const ushort* src = isB ? Bt : A;
    const int rbase = isB ? tN : tM;
    const int L = c * 8192 + tid * 16;
    const int row = L >> 7;
    const int colb = (L & 127) ^ ((row & 7) << 4);
    gload_lds16((ushort*)(dst + L), &src[(size_t)(rbase + row) * K + k0 + (colb >> 1)]);
  };
  auto stageAll = [&](int buf, int k0) {
    stage1(buf, k0, 1, 0); stage1(buf, k0, 1, 1); stage1(buf, k0, 1, 2);
    stage1(buf, k0, 1, 3); stage1(buf, k0, 1, 4);
    stage1(buf, k0, 0, 0); stage1(buf, k0, 0, 1);
    stage1(buf, k0, 0, 2); stage1(buf, k0, 0, 3);
  };
  auto rdA = [&](const char* base, int mo, int cb, short8* dst) {
#pragma unroll
    for (int m = 0; m < 4; ++m)
      dst[m] = *(const short8*)(base + (wm * 128 + (mo + m) * 16 + fr) * 128 + cb);
  };
  auto rdB = [&](const char* base, int cb, short8* dst) {
#pragma unroll
    for (int n = 0; n < 5; ++n)
      dst[n] = *(const short8*)(base + 32768 + (wn * 80 + n * 16 + fr) * 128 + cb);
  };

  stageAll(0, 0);
  __syncthreads();

  int cur = 0;
#pragma unroll 1
  for (int kt = 0; kt < NT; ++kt) {
    const int nxt = cur ^ 1;
    if (kt + 1 < NT) stageAll(nxt, (kt + 1) << 6);
    const char* base = lds + cur * 73728;

    short8 afA[4], afB[4], afC[4], afD[4], bf0[5], bf1[5];
    rdA(base, 0, c0b, afA);
    rdB(base, c0b, bf0);
#pragma unroll
    for (int m = 0; m < 4; ++m)
#pragma unroll
      for (int n = 0; n < 5; ++n)
        acc[m][n] = __builtin_amdgcn_mfma_f32_16x16x32_bf16(afA[m], bf0[n], acc[m][n], 0, 0, 0);
    rdA(base, 4, c0b, afB);
#pragma unroll
    for (int m = 0; m < 4; ++m)
#pragma unroll
      for (int n = 0; n < 5; ++n)
        acc[m + 4][n] = __builtin_amdgcn_mfma_f32_16x16x32_bf16(afB[m], bf0[n], acc[m + 4][n], 0, 0, 0);
    rdA(base, 0, c1b, afC);
    rdB(base, c1b, bf1);
#pragma unroll
    for (int m = 0; m < 4; ++m)
#pragma unroll
      for (int n = 0; n < 5; ++n)
        acc[m][n] = __builtin_amdgcn_mfma_f32_16x16x32_bf16(afC[m], bf1[n], acc[m][n], 0, 0, 0);
    rdA(base, 4, c1b, afD);
#pragma unroll
    for (int m = 0; m < 4; ++m)
#pragma unroll
      for (int n = 0; n < 5; ++n)
        acc[m + 4][n] = __builtin_amdgcn_mfma_f32_16x16x32_bf16(afD[m], bf1[n], acc[m + 4][n], 0, 0, 0);

    __syncthreads();
    cur = nxt;
  }

#pragma unroll
  for (int m = 0; m < 8; ++m) {
    const int rbase = tM + wm * 128 + m * 16 + (lane >> 4) * 4;
#pragma unroll
    for (int n = 0; n < 5; ++n) {
      const int col = tN + wn * 80 + n * 16 + fr;
#pragma unroll
      for (int j = 0; j < 4; ++j)
        Cout[(size_t)(rbase + j) * N + col] = acc[m][n][j] + bias[col];
    }
  }
}

// ---------------- attention (MFMA) ----------------
// stats: subsampled 1/16 of qtiles; std rel-err ~6e-4.
#define NSAMP ((double)B_ * H_ * (S_ / 16) * STXT_)
#define KVK(bh, t)  ((((size_t)(bh)) * STXT_ + (t)) * D_)
#define IPK(bh, t)  ((((size_t)(bh)) * TIP_ + (t)) * D_)

__global__ __launch_bounds__(256, 4)
void stats_mfma(const ushort* __restrict__ qb, const ushort* __restrict__ kvb,
                float* __restrict__ stats) {
  __shared__ ushort Ks[80 * 64];
  __shared__ float part[4][2];
  const int qt = blockIdx.x * 16, bh = blockIdx.y;
  const int tid = threadIdx.x, lane = tid & 63, wid = tid >> 6;
  for (int c = tid; c < 80 * 8; c += 256) {
    int row = c >> 3, col = (c & 7) * 8;
    uint4 v = {0, 0, 0, 0};
    if (row < STXT_)
      v = *(const uint4*)&kvb[KVK(bh, row) + col];
    *(uint4*)((char*)Ks + kswz(row, col * 2)) = v;
  }
  __syncthreads();
  const int fr = lane & 15, fk = lane >> 4;
  const int wr = wid * 32;
  short8 a0[2], a1[2];
#pragma unroll
  for (int m = 0; m < 2; ++m) {
    const ushort* qp = &qb[((size_t)bh * S_ + qt * 128 + wr + m * 16 + fr) * D_];
    a0[m] = *(const short8*)&qp[fk * 8];
    a1[m] = *(const short8*)&qp[32 + fk * 8];
  }
  f32x4 acc[2][5];
#pragma unroll
  for (int m = 0; m < 2; ++m)
#pragma unroll
    for (int n = 0; n < 5; ++n) acc[m][n] = (f32x4){0.f, 0.f, 0.f, 0.f};
#pragma unroll
  for (int n = 0; n < 5; ++n) {
    short8 b0 = *(const short8*)((const char*)Ks + kswz(n * 16 + fr, fk * 16));
    short8 b1 = *(const short8*)((const char*)Ks + kswz(n * 16 + fr, 64 + fk * 16));
#pragma unroll
    for (int m = 0; m < 2; ++m) {
      acc[m][n] = __builtin_amdgcn_mfma_f32_16x16x32_bf16(a0[m], b0, acc[m][n], 0, 0, 0);
      acc[m][n] = __builtin_amdgcn_mfma_f32_16x16x32_bf16(a1[m], b1, acc[m][n], 0, 0, 0);
    }
  }
  float sum = 0.f, ss = 0.f;
#pragma unroll
  for (int m = 0; m < 2; ++m)
#pragma unroll
    for (int n = 0; n < 5; ++n)
#pragma unroll
      for (int j = 0; j < 4; ++j) {
        float v = acc[m][n][j];
        sum += v;
        ss = fmaf(v, v, ss);
      }
#pragma unroll
  for (int msk = 1; msk < 64; msk <<= 1) {
    sum += __shfl_xor(sum, msk, 64);
    ss  += __shfl_xor(ss,  msk, 64);
  }
  if (lane == 0) { part[wid][0] = sum; part[wid][1] = ss; }
  __syncthreads();
  if (tid == 0) {
    float s = 0.f, q2 = 0.f;
#pragma unroll
    for (int w = 0; w < 4; ++w) { s += part[w][0]; q2 += part[w][1]; }
    atomicAdd(&stats[0], s);
    atomicAdd(&stats[1], q2);
  }
}

// Swapped-QK^T attention (R15 structure: wave-private Pl, wave-local fences,
// coalesced O via LDS bounce).  This round: all attention-side inputs are
// head-major, so per-wave Q/K/V accesses tile contiguous regions.
__global__ __launch_bounds__(256, 3)
void attn_mfma(const ushort* __restrict__ qb, const ushort* __restrict__ kvb,
               const ushort* __restrict__ ipkvb, const float* __restrict__ regionT,
               const float* __restrict__ stats, const float* __restrict__ sigma,
               ushort* __restrict__ hb) {
  __shared__ ushort Ks[96 * 64];
  __shared__ ushort Vt2[12 * 64 * 8];
  __shared__ ushort Pl[128 * 104];      // P probs; after PV, reused as O staging
  const int qt0 = blockIdx.x * 4;
  const int bh = blockIdx.y;
  const int b = bh / H_, h = bh % H_;
  const int tid = threadIdx.x, lane = tid & 63, wid = tid >> 6;
  const int fr = lane & 15, fk = lane >> 4;
  const int wr = wid * 32;
  const ushort* kvbV  = kvb   + (size_t)B_ * H_ * STXT_ * D_;
  const ushort* ipkvV = ipkvb + (size_t)B_ * H_ * TIP_ * D_;

  for (int c = tid; c < 96 * 8; c += 256) {
    int row = c >> 3, col = (c & 7) * 8;
    uint4 v = {0, 0, 0, 0};
    if (row < STXT_)
      v = *(const uint4*)&kvb[KVK(bh, row) + col];
    else if (row >= 80 && row < 80 + TIP_)
      v = *(const uint4*)&ipkvb[IPK(bh, row - 80) + col];
    *(uint4*)((char*)Ks + kswz(row, col * 2)) = v;
  }
  for (int c = tid; c < 12 * 64; c += 256) {
    int d = c & 63, kc = c >> 6;
    ushort tv[8];
#pragma unroll
    for (int i = 0; i < 8; ++i) {
      int k = kc * 8 + i;
      ushort v = 0;
      if (k < STXT_)
        v = kvbV[KVK(bh, k) + d];
      else if (k >= 80 && k < 80 + TIP_)
        v = ipkvV[IPK(bh, k - 80) + d];
      tv[i] = v;
    }
    uint4 w;
    w.x = (uint)tv[0] | ((uint)tv[1] << 16);
    w.y = (uint)tv[2] | ((uint)tv[3] << 16);
    w.z = (uint)tv[4] | ((uint)tv[5] << 16);
    w.w = (uint)tv[6] | ((uint)tv[7] << 16);
    *(uint4*)&Vt2[(size_t)c * 8] = w;
  }
  __syncthreads();

  float bscale;
  {
    float sum = stats[0], sumsq = stats[1];
    const float Nf = (float)NSAMP;
    float var = (sumsq - sum * (sum / Nf)) / (Nf - 1.0f);
    bscale = sigma[0] * sqrtf(var);
  }
  const int fk4 = fk * 4;

#pragma unroll 1
  for (int qq = 0; qq < 4; ++qq) {
    const int qt = qt0 + qq;
    short8 qf0[2], qf1[2];
#pragma unroll
    for (int g = 0; g < 2; ++g) {
      const ushort* qp = &qb[((size_t)bh * S_ + qt * 128 + wr + g * 16 + fr) * D_];
      qf0[g] = *(const short8*)&qp[fk * 8];
      qf1[g] = *(const short8*)&qp[32 + fk * 8];
    }
    f32x4 acc[2][6];
#pragma unroll
    for (int g = 0; g < 2; ++g)
#pragma unroll
      for (int n = 0; n < 6; ++n) acc[g][n] = (f32x4){0.f, 0.f, 0.f, 0.f};
    __builtin_amdgcn_s_setprio(1);
#pragma unroll
    for (int n = 0; n < 6; ++n) {
      short8 k0 = *(const short8*)((const char*)Ks + kswz(n * 16 + fr, fk * 16));
      short8 k1 = *(const short8*)((const char*)Ks + kswz(n * 16 + fr, 64 + fk * 16));
#pragma unroll
      for (int g = 0; g < 2; ++g) {
        acc[g][n] = __builtin_amdgcn_mfma_f32_16x16x32_bf16(k0, qf0[g], acc[g][n], 0, 0, 0);
        acc[g][n] = __builtin_amdgcn_mfma_f32_16x16x32_bf16(k1, qf1[g], acc[g][n], 0, 0, 0);
      }
    }
    __builtin_amdgcn_s_setprio(0);

#pragma unroll
    for (int g = 0; g < 2; ++g) {
      const int q = wr + g * 16 + fr;
      const int qrow = qt * 128 + q;
      const float* rT = &regionT[(size_t)b * STXT_ * S_ + qrow];
      float p[5][4];
      float mloc = -1e30f;
#pragma unroll
      for (int n = 0; n < 5; ++n)
#pragma unroll
        for (int j = 0; j < 4; ++j) {
          int key = n * 16 + fk4 + j;
          float s = -1e30f;
          if (key < STXT_) s = fmaf(rT[(size_t)key * S_], bscale, acc[g][n][j]);
          p[n][j] = s;
          mloc = fmaxf(mloc, s);
        }
      mloc = fmaxf(mloc, __shfl_xor(mloc, 16, 64));
      mloc = fmaxf(mloc, __shfl_xor(mloc, 32, 64));
      float lsum = 0.f;
#pragma unroll
      for (int n = 0; n < 5; ++n)
#pragma unroll
        for (int j = 0; j < 4; ++j) {
          float e = __expf(p[n][j] - mloc);
          p[n][j] = e;
          lsum += e;
        }
      lsum += __shfl_xor(lsum, 16, 64);
      lsum += __shfl_xor(lsum, 32, 64);
      const float rl = 1.0f / lsum;
#pragma unroll
      for (int n = 0; n < 5; ++n)
#pragma unroll
        for (int j = 0; j < 4; ++j) {
          int key = n * 16 + fk4 + j;
          if (key < STXT_) Pl[q * 104 + key] = f2bf(p[n][j] * rl);
        }
      if (fk == 0) {
        float s0 = acc[g][5][0], s1 = acc[g][5][1];
        float s2 = acc[g][5][2], s3 = acc[g][5][3];
        float mi = fmaxf(fmaxf(s0, s1), fmaxf(s2, s3));
        float e0 = __expf(s0 - mi), e1 = __expf(s1 - mi);
        float e2 = __expf(s2 - mi), e3 = __expf(s3 - mi);
        float rli = 1.0f / (e0 + e1 + e2 + e3);
        Pl[q * 104 + 80] = f2bf(e0 * rli);
        Pl[q * 104 + 81] = f2bf(e1 * rli);
        Pl[q * 104 + 82] = f2bf(e2 * rli);
        Pl[q * 104 + 83] = f2bf(e3 * rli);
      }
    }

    // wave-local fence: softmax ds_writes -> PV ds_reads
    asm volatile("s_waitcnt lgkmcnt(0)" ::: "memory");
    __builtin_amdgcn_sched_barrier(0);

    f32x4 o[2][4];
#pragma unroll
    for (int m = 0; m < 2; ++m)
#pragma unroll
      for (int n = 0; n < 4; ++n) o[m][n] = (f32x4){0.f, 0.f, 0.f, 0.f};
    __builtin_amdgcn_s_setprio(1);
#pragma unroll
    for (int kc = 0; kc < 3; ++kc) {
      const int kb8 = kc * 32;
      short8 pa0 = *(const short8*)&Pl[(wr + fr) * 104 + kb8 + fk * 8];
      short8 pa1 = *(const short8*)&Pl[(wr + 16 + fr) * 104 + kb8 + fk * 8];
#pragma unroll
      for (int n = 0; n < 4; ++n) {
        short8 vf = *(const short8*)&Vt2[(size_t)((kc * 4 + fk) * 64 + n * 16 + fr) * 8];
        o[0][n] = __builtin_amdgcn_mfma_f32_16x16x32_bf16(pa0, vf, o[0][n], 0, 0, 0);
        o[1][n] = __builtin_amdgcn_mfma_f32_16x16x32_bf16(pa1, vf, o[1][n], 0, 0, 0);
      }
    }
    __builtin_amdgcn_s_setprio(0);

    // wave-local fence: PV ds_reads done -> O staging overwrites Pl rows
    asm volatile("s_waitcnt lgkmcnt(0)" ::: "memory");
    __builtin_amdgcn_sched_barrier(0);

#pragma unroll
    for (int m = 0; m < 2; ++m)
#pragma unroll
      for (int n = 0; n < 4; ++n)
#pragma unroll
        for (int j = 0; j < 4; ++j)
          Pl[(wr + m * 16 + fk4 + j) * 104 + n * 16 + fr] = f2bf(o[m][n][j]);

    asm volatile("s_waitcnt lgkmcnt(0)" ::: "memory");
    __builtin_amdgcn_sched_barrier(0);

#pragma unroll
    for (int c = 0; c < 4; ++c) {
      const int lrow = wr + c * 8 + (lane >> 3);          // wave-private row
      uint4 w = *(const uint4*)&Pl[lrow * 104 + (lane & 7) * 8];
      const int grow = qt * 128 + lrow;
      *(uint4*)&hb[((size_t)b * S_ + grow) * C_ + h * D_ + (lane & 7) * 8] = w;
    }

    // wave-local fence: O-staging reads done -> next qq's Pl writes
    asm volatile("s_waitcnt lgkmcnt(0)" ::: "memory");
    __builtin_amdgcn_sched_barrier(0);
  }
}

// ---------------- launcher ----------------

extern "C" void kernel_launch(void* const* d_in, const int* in_sizes, int n_in,
                              void* d_out, int out_size, void* d_ws, size_t ws_size,
                              hipStream_t stream) {
  const float* hid    = (const float*)d_in[0];
  const float* enc    = (const float*)d_in[1];
  const float* ipx    = (const float*)d_in[2];
  const float* region = (const float*)d_in[3];
  const float* sigma  = (const float*)d_in[4];
  const float* wq     = (const float*)d_in[5];
  const float* wk     = (const float*)d_in[6];
  const float* wv     = (const float*)d_in[7];
  const float* wkip   = (const float*)d_in[8];
  const float* wvip   = (const float*)d_in[9];
  const float* wout   = (const float*)d_in[10];
  const float* bout   = (const float*)d_in[11];

  char* ws = (char*)d_ws;
  size_t off = 0;
  auto alloc = [&](size_t bytes) {
    char* p = ws + off;
    off += (bytes + 255) & ~(size_t)255;
    return p;
  };
  float*  stats  = (float*)alloc(16);
  ushort* hb     = (ushort*)alloc((size_t)B_ * S_ * C_ * 2);   // hidden bf16, later h bf16
  ushort* qb     = (ushort*)alloc((size_t)B_ * S_ * C_ * 2);   // Q head-major, pre-scaled
  ushort* encb   = (ushort*)alloc((size_t)B_ * STXT_ * CC_ * 2);
  ushort* ipb    = (ushort*)alloc((size_t)B_ * TIP_ * CC_ * 2);
  ushort* wqT    = (ushort*)alloc((size_t)C_ * C_ * 2);
  ushort* wkvT   = (ushort*)alloc((size_t)KVLD * CC_ * 2);
  ushort* wkvipT = (ushort*)alloc((size_t)KVLD * CC_ * 2);
  ushort* woutT  = (ushort*)alloc((size_t)C_ * C_ * 2);
  ushort* kvb    = (ushort*)alloc((size_t)B_ * STXT_ * KVLD * 2);  // head-major K|V
  ushort* ipkvb  = (ushort*)alloc((size_t)B_ * TIP_ * KVLD * 2);   // head-major K|V
  float*  regionT= (float*)alloc((size_t)B_ * STXT_ * S_ * 4);

  hipMemsetAsync(stats, 0, 16, stream);
  prep_all<<<PREP_TOTAL, 256, 0, stream>>>(hid, enc, ipx, region,
                                           wq, wk, wv, wkip, wvip, wout,
                                           hb, encb, ipb, wqT, wkvT, wkvipT,
                                           woutT, regionT);

  gemm_fused<<<296, 512, 0, stream>>>(hb, wqT, qb, encb, wkvT, kvb,
                                      ipb, wkvipT, ipkvb);

  stats_mfma<<<dim3(2, B_ * H_), 256, 0, stream>>>(qb, kvb, stats);
  attn_mfma<<<dim3(S_ / 512, B_ * H_), 256, 0, stream>>>(qb, kvb, ipkvb, regionT,
                                                         stats, sigma, hb);
  gemm11<<<256, 512, 0, stream>>>(hb, woutT, (float*)d_out, bout, C_, C_);
}

// Round 17
// 193.964 us; speedup vs baseline: 1.0214x; 1.0214x over previous
//
#include <hip/hip_runtime.h>
#include <hip/hip_bf16.h>
#include <stdint.h>

#define B_    4
#define S_    4096
#define STXT_ 77
#define C_    1280
#define CC_   768
#define H_    20
#define TIP_  4
#define D_    64
#define KVLD  2560

using short8 = __attribute__((ext_vector_type(8))) short;
using f32x4  = __attribute__((ext_vector_type(4))) float;

__device__ __forceinline__ ushort f2bf(float f) {
  union { float f; uint32_t u; } x; x.f = f;
  uint32_t r = (x.u + 0x7FFFu + ((x.u >> 16) & 1u)) >> 16;
  return (ushort)r;
}

__device__ __forceinline__ void gload_lds16(ushort* lds, const ushort* g) {
  __builtin_amdgcn_global_load_lds(
      (const __attribute__((address_space(1))) void*)g,
      (__attribute__((address_space(3))) void*)lds, 16, 0, 0);
}

// XOR-swizzle for bf16 [rows][64] LDS tiles (row stride 128B)
__device__ __forceinline__ int kswz(int row, int colByte) {
  return row * 128 + (colByte ^ ((row & 7) << 4));
}

// ---------------- fused prep kernel ----------------
#define PREP_CONV   2048
#define PREP_TW     7040
#define PREP_TOTAL  (PREP_CONV + PREP_TW + 1536)

__global__ __launch_bounds__(256)
void prep_all(const float* __restrict__ hid, const float* __restrict__ enc,
              const float* __restrict__ ipx, const float* __restrict__ region,
              const float* __restrict__ wq, const float* __restrict__ wk,
              const float* __restrict__ wv, const float* __restrict__ wkip,
              const float* __restrict__ wvip, const float* __restrict__ wout,
              ushort* __restrict__ hb, ushort* __restrict__ encb,
              ushort* __restrict__ ipb, ushort* __restrict__ wqT,
              ushort* __restrict__ wkvT, ushort* __restrict__ wkvipT,
              ushort* __restrict__ woutT, float* __restrict__ regionT) {
  __shared__ float t[32][33];
  const int bid = blockIdx.x;
  const int tid = threadIdx.x;

  if (bid < PREP_CONV) {
    const size_t N0 = (size_t)B_ * S_ * C_;
    const size_t N1 = (size_t)B_ * STXT_ * CC_;
    const size_t N2 = (size_t)B_ * TIP_ * CC_;
    const size_t TOT4 = (N0 + N1 + N2) / 4;
    for (size_t i4 = (size_t)bid * 256 + tid; i4 < TOT4; i4 += (size_t)PREP_CONV * 256) {
      size_t i = i4 * 4;
      const float* src; ushort* dst; size_t off;
      if (i < N0)            { src = hid; dst = hb;   off = i; }
      else if (i < N0 + N1)  { src = enc; dst = encb; off = i - N0; }
      else                   { src = ipx; dst = ipb;  off = i - N0 - N1; }
      float4 v = *(const float4*)&src[off];
      ushort4 w;
      w.x = f2bf(v.x); w.y = f2bf(v.y); w.z = f2bf(v.z); w.w = f2bf(v.w);
      *(ushort4*)&dst[off] = w;
    }
    return;
  }

  const int tx = tid & 31, ty = tid >> 5;

  if (bid < PREP_CONV + PREP_TW) {
    const int u = bid - PREP_CONV;
    const float* src; ushort* dst; int K, n0, k0;
    if (u < 1600)        { src = wq;   dst = wqT;   K = C_;  n0 = (u % 40) * 32;  k0 = (u / 40) * 32; }
    else if (u < 5440) {
      const int w = u - 1600, zi = w / 960, r = w % 960;
      K = CC_; n0 = (r % 40) * 32; k0 = (r / 40) * 32;
      switch (zi) {
        case 0:  src = wk;   dst = wkvT;                       break;
        case 1:  src = wv;   dst = wkvT + (size_t)C_ * CC_;    break;
        case 2:  src = wkip; dst = wkvipT;                     break;
        default: src = wvip; dst = wkvipT + (size_t)C_ * CC_;  break;
      }
    }
    else                 { const int w = u - 5440;
                           src = wout; dst = woutT; K = C_;  n0 = (w % 40) * 32;  k0 = (w / 40) * 32; }
#pragma unroll
    for (int r = 0; r < 4; ++r) {
      int kk = k0 + ty + r * 8;
      t[ty + r * 8][tx] = src[(size_t)kk * C_ + n0 + tx];
    }
    __syncthreads();
#pragma unroll
    for (int r = 0; r < 4; ++r) {
      int nn = n0 + ty + r * 8;
      dst[(size_t)nn * K + k0 + tx] = f2bf(t[tx][ty + r * 8]);
    }
    return;
  }

  {
    const int u = bid - PREP_CONV - PREP_TW;   // [0,1536): B_ * 3 * 128
    const int b = u / 384;
    const int r = u % 384;
    const int s0 = (r % 128) * 32;
    const int k0 = (r / 128) * 32;
#pragma unroll
    for (int rr = 0; rr < 4; ++rr) {
      int ss = s0 + ty + rr * 8;
      int kk = k0 + tx;
      t[ty + rr * 8][tx] = (kk < STXT_) ? region[((size_t)b * S_ + ss) * STXT_ + kk] : 0.f;
    }
    __syncthreads();
#pragma unroll
    for (int rr = 0; rr < 4; ++rr) {
      int kk = k0 + ty + rr * 8;
      if (kk < STXT_)
        regionT[((size_t)b * STXT_ + kk) * S_ + s0 + tx] = t[tx][ty + rr * 8];
    }
  }
}

// ------ fused big GEMM launch: blocks [0,256) = Q-proj 256x320 (R8 body);
//        blocks [256,296) = K/V + IP projections 128x256, K=768 ------
__global__ __launch_bounds__(512, 2)
void gemm_fused(const ushort* __restrict__ hb, const ushort* __restrict__ wqT,
                ushort* __restrict__ qb, const ushort* __restrict__ encb,
                const ushort* __restrict__ wkvT, ushort* __restrict__ kvb,
                const ushort* __restrict__ ipb, const ushort* __restrict__ wkvipT,
                ushort* __restrict__ ipkvb) {
  __shared__ char lds[147456];
  const int tid = threadIdx.x, lane = tid & 63, wid = tid >> 6;
  const int fr = lane & 15, fk = lane >> 4;
  const int swzf = (fr & 7) << 4;
  const int c0b = (fk * 16) ^ swzf;
  const int c1b = (64 + fk * 16) ^ swzf;

  if (blockIdx.x < 256) {
    const int NT = C_ >> 6;                   // 20 K-tiles
    int wg = blockIdx.x;
    wg = (wg & 7) * 32 + (wg >> 3);           // XCD swizzle over 256 blocks
    const int tM = (wg / 4) * 256;
    const int tN = (wg % 4) * 320;
    const int wm = wid >> 2, wn = wid & 3;    // wave tile: rows wm*128, cols wn*80

    f32x4 acc[8][5];
#pragma unroll
    for (int m = 0; m < 8; ++m)
#pragma unroll
      for (int n = 0; n < 5; ++n) acc[m][n] = (f32x4){0.f, 0.f, 0.f, 0.f};

    auto stage1 = [&](int buf, int k0, int isB, int c) {
      char* dst = lds + buf * 73728 + (isB ? 32768 : 0);
      const ushort* src = isB ? wqT : hb;
      const int rbase = isB ? tN : tM;
      const int L = c * 8192 + tid * 16;
      const int row = L >> 7;
      const int colb = (L & 127) ^ ((row & 7) << 4);
      gload_lds16((ushort*)(dst + L), &src[(size_t)(rbase + row) * C_ + k0 + (colb >> 1)]);
    };
    auto stageAll = [&](int buf, int k0) {
      stage1(buf, k0, 1, 0); stage1(buf, k0, 1, 1); stage1(buf, k0, 1, 2);
      stage1(buf, k0, 1, 3); stage1(buf, k0, 1, 4);
      stage1(buf, k0, 0, 0); stage1(buf, k0, 0, 1);
      stage1(buf, k0, 0, 2); stage1(buf, k0, 0, 3);
    };
    auto rdA = [&](const char* base, int mo, int cb, short8* dst) {
#pragma unroll
      for (int m = 0; m < 4; ++m)
        dst[m] = *(const short8*)(base + (wm * 128 + (mo + m) * 16 + fr) * 128 + cb);
    };
    auto rdB = [&](const char* base, int cb, short8* dst) {
#pragma unroll
      for (int n = 0; n < 5; ++n)
        dst[n] = *(const short8*)(base + 32768 + (wn * 80 + n * 16 + fr) * 128 + cb);
    };

    stageAll(0, 0);
    __syncthreads();

    int cur = 0;
#pragma unroll 1
    for (int kt = 0; kt < NT; ++kt) {
      const int nxt = cur ^ 1;
      if (kt + 1 < NT) stageAll(nxt, (kt + 1) << 6);
      const char* Bb_ = lds + cur * 73728;

      short8 afA[4], afB[4], afC[4], afD[4], bf0[5], bf1[5];
      rdA(Bb_, 0, c0b, afA);
      rdB(Bb_, c0b, bf0);
#pragma unroll
      for (int m = 0; m < 4; ++m)
#pragma unroll
        for (int n = 0; n < 5; ++n)
          acc[m][n] = __builtin_amdgcn_mfma_f32_16x16x32_bf16(afA[m], bf0[n], acc[m][n], 0, 0, 0);
      rdA(Bb_, 4, c0b, afB);
#pragma unroll
      for (int m = 0; m < 4; ++m)
#pragma unroll
        for (int n = 0; n < 5; ++n)
          acc[m + 4][n] = __builtin_amdgcn_mfma_f32_16x16x32_bf16(afB[m], bf0[n], acc[m + 4][n], 0, 0, 0);
      rdA(Bb_, 0, c1b, afC);
      rdB(Bb_, c1b, bf1);
#pragma unroll
      for (int m = 0; m < 4; ++m)
#pragma unroll
        for (int n = 0; n < 5; ++n)
          acc[m][n] = __builtin_amdgcn_mfma_f32_16x16x32_bf16(afC[m], bf1[n], acc[m][n], 0, 0, 0);
      rdA(Bb_, 4, c1b, afD);
#pragma unroll
      for (int m = 0; m < 4; ++m)
#pragma unroll
        for (int n = 0; n < 5; ++n)
          acc[m + 4][n] = __builtin_amdgcn_mfma_f32_16x16x32_bf16(afD[m], bf1[n], acc[m + 4][n], 0, 0, 0);

      __syncthreads();
      cur = nxt;
    }

#pragma unroll
    for (int m = 0; m < 8; ++m) {
      const int rbase = tM + wm * 128 + m * 16 + (lane >> 4) * 4;
#pragma unroll
      for (int n = 0; n < 5; ++n) {
        const int col = tN + wn * 80 + n * 16 + fr;
#pragma unroll
        for (int j = 0; j < 4; ++j)
          qb[(size_t)(rbase + j) * C_ + col] = f2bf(acc[m][n][j] * 0.125f);
      }
    }
    return;
  }

  // ---------------- K/V + IP projection path: 128x256, K=768, 12 tiles ----------------
  {
    int u = blockIdx.x - 256;                 // [0,40)
    const ushort* A; const ushort* Bt; ushort* Co; int M, tM, tN;
    if (u < 30) { A = encb; Bt = wkvT;   Co = kvb;   M = B_ * STXT_;
                  tM = (u / 10) * 128; tN = (u % 10) * 256; }
    else        { u -= 30; A = ipb; Bt = wkvipT; Co = ipkvb; M = B_ * TIP_;
                  tM = 0; tN = u * 256; }
    const int wm = wid >> 2, wn = wid & 3;    // rows wm*64, cols wn*64

    f32x4 acc[4][4];
#pragma unroll
    for (int m = 0; m < 4; ++m)
#pragma unroll
      for (int n = 0; n < 4; ++n) acc[m][n] = (f32x4){0.f, 0.f, 0.f, 0.f};

    auto stage1k = [&](int buf, int k0, int isB, int c) {
      char* dst = lds + buf * 49152 + (isB ? 16384 : 0);
      const ushort* src = isB ? Bt : A;
      const int L = c * 8192 + tid * 16;
      const int row = L >> 7;
      const int colb = (L & 127) ^ ((row & 7) << 4);
      int r = isB ? (tN + row) : min(tM + row, M - 1);
      gload_lds16((ushort*)(dst + L), &src[(size_t)r * CC_ + k0 + (colb >> 1)]);
    };
    auto stageAllk = [&](int buf, int k0) {
      stage1k(buf, k0, 1, 0); stage1k(buf, k0, 1, 1);
      stage1k(buf, k0, 1, 2); stage1k(buf, k0, 1, 3);
      stage1k(buf, k0, 0, 0); stage1k(buf, k0, 0, 1);
    };
    auto rdAk = [&](const char* base, int cb, short8* dst) {
#pragma unroll
      for (int m = 0; m < 4; ++m)
        dst[m] = *(const short8*)(base + (wm * 64 + m * 16 + fr) * 128 + cb);
    };
    auto rdBk = [&](const char* base, int cb, short8* dst) {
#pragma unroll
      for (int n = 0; n < 4; ++n)
        dst[n] = *(const short8*)(base + 16384 + (wn * 64 + n * 16 + fr) * 128 + cb);
    };

    stageAllk(0, 0);
    __syncthreads();

    int cur = 0;
#pragma unroll 1
    for (int kt = 0; kt < 12; ++kt) {
      const int nxt = cur ^ 1;
      if (kt + 1 < 12) stageAllk(nxt, (kt + 1) << 6);
      const char* base = lds + cur * 49152;

      short8 af0[4], af1[4], bk0[4], bk1[4];
      rdAk(base, c0b, af0);
      rdBk(base, c0b, bk0);
#pragma unroll
      for (int m = 0; m < 4; ++m)
#pragma unroll
        for (int n = 0; n < 4; ++n)
          acc[m][n] = __builtin_amdgcn_mfma_f32_16x16x32_bf16(af0[m], bk0[n], acc[m][n], 0, 0, 0);
      rdAk(base, c1b, af1);
      rdBk(base, c1b, bk1);
#pragma unroll
      for (int m = 0; m < 4; ++m)
#pragma unroll
        for (int n = 0; n < 4; ++n)
          acc[m][n] = __builtin_amdgcn_mfma_f32_16x16x32_bf16(af1[m], bk1[n], acc[m][n], 0, 0, 0);

      __syncthreads();
      cur = nxt;
    }

#pragma unroll
    for (int m = 0; m < 4; ++m) {
      const int rbase = tM + wm * 64 + m * 16 + (lane >> 4) * 4;
#pragma unroll
      for (int n = 0; n < 4; ++n) {
        const int col = tN + wn * 64 + n * 16 + fr;
#pragma unroll
        for (int j = 0; j < 4; ++j) {
          int row = rbase + j;
          if (row < M) Co[(size_t)row * KVLD + col] = f2bf(acc[m][n][j]);
        }
      }
    }
  }
}

// ------ out-proj GEMM: 256x320 tile, BK=64, 2-buffer, one barrier/K-tile ------
__global__ __launch_bounds__(512, 2)
void gemm11(const ushort* __restrict__ A, const ushort* __restrict__ Bt,
            float* __restrict__ Cout, const float* __restrict__ bias,
            int N, int K) {
  __shared__ char lds[147456];
  const int NT = K >> 6;
  int wg = blockIdx.x;
  wg = (wg & 7) * ((int)gridDim.x >> 3) + (wg >> 3);
  const int nTn = N / 320;
  const int tM = (wg / nTn) * 256;
  const int tN = (wg % nTn) * 320;

  const int tid = threadIdx.x, lane = tid & 63, wid = tid >> 6;
  const int wm = wid >> 2, wn = wid & 3;
  const int fr = lane & 15, fk = lane >> 4;
  const int swzf = (fr & 7) << 4;
  const int c0b = (fk * 16) ^ swzf;
  const int c1b = (64 + fk * 16) ^ swzf;

  f32x4 acc[8][5];
#pragma unroll
  for (int m = 0; m < 8; ++m)
#pragma unroll
    for (int n = 0; n < 5; ++n) acc[m][n] = (f32x4){0.f, 0.f, 0.f, 0.f};

  auto stage1 = [&](int buf, int k0, int isB, int c) {
    char* dst = lds + buf * 73728 + (isB ? 32768 : 0);
    const ushort* src = isB ? Bt : A;
    const int rbase = isB ? tN : tM;
    const int L = c * 8192 + tid * 16;
    const int row = L >> 7;
    const int colb = (L & 127) ^ ((row & 7) << 4);
    gload_lds16((ushort*)(dst + L), &src[(size_t)(rbase + row) * K + k0 + (colb >> 1)]);
  };
  auto stageAll = [&](int buf, int k0) {
    stage1(buf, k0, 1, 0); stage1(buf, k0, 1, 1); stage1(buf, k0, 1, 2);
    stage1(buf, k0, 1, 3); stage1(buf, k0, 1, 4);
    stage1(buf, k0, 0, 0); stage1(buf, k0, 0, 1);
    stage1(buf, k0, 0, 2); stage1(buf, k0, 0, 3);
  };
  auto rdA = [&](const char* base, int mo, int cb, short8* dst) {
#pragma unroll
    for (int m = 0; m < 4; ++m)
      dst[m] = *(const short8*)(base + (wm * 128 + (mo + m) * 16 + fr) * 128 + cb);
  };
  auto rdB = [&](const char* base, int cb, short8* dst) {
#pragma unroll
    for (int n = 0; n < 5; ++n)
      dst[n] = *(const short8*)(base + 32768 + (wn * 80 + n * 16 + fr) * 128 + cb);
  };

  stageAll(0, 0);
  __syncthreads();

  int cur = 0;
#pragma unroll 1
  for (int kt = 0; kt < NT; ++kt) {
    const int nxt = cur ^ 1;
    if (kt + 1 < NT) stageAll(nxt, (kt + 1) << 6);
    const char* base = lds + cur * 73728;

    short8 afA[4], afB[4], afC[4], afD[4], bf0[5], bf1[5];
    rdA(base, 0, c0b, afA);
    rdB(base, c0b, bf0);
#pragma unroll
    for (int m = 0; m < 4; ++m)
#pragma unroll
      for (int n = 0; n < 5; ++n)
        acc[m][n] = __builtin_amdgcn_mfma_f32_16x16x32_bf16(afA[m], bf0[n], acc[m][n], 0, 0, 0);
    rdA(base, 4, c0b, afB);
#pragma unroll
    for (int m = 0; m < 4; ++m)
#pragma unroll
      for (int n = 0; n < 5; ++n)
        acc[m + 4][n] = __builtin_amdgcn_mfma_f32_16x16x32_bf16(afB[m], bf0[n], acc[m + 4][n], 0, 0, 0);
    rdA(base, 0, c1b, afC);
    rdB(base, c1b, bf1);
#pragma unroll
    for (int m = 0; m < 4; ++m)
#pragma unroll
      for (int n = 0; n < 5; ++n)
        acc[m][n] = __builtin_amdgcn_mfma_f32_16x16x32_bf16(afC[m], bf1[n], acc[m][n], 0, 0, 0);
    rdA(base, 4, c1b, afD);
#pragma unroll
    for (int m = 0; m < 4; ++m)
#pragma unroll
      for (int n = 0; n < 5; ++n)
        acc[m + 4][n] = __builtin_amdgcn_mfma_f32_16x16x32_bf16(afD[m], bf1[n], acc[m + 4][n], 0, 0, 0);

    __syncthreads();
    cur = nxt;
  }

#pragma unroll
  for (int m = 0; m < 8; ++m) {
    const int rbase = tM + wm * 128 + m * 16 + (lane >> 4) * 4;
#pragma unroll
    for (int n = 0; n < 5; ++n) {
      const int col = tN + wn * 80 + n * 16 + fr;
#pragma unroll
      for (int j = 0; j < 4; ++j)
        Cout[(size_t)(rbase + j) * N + col] = acc[m][n][j] + bias[col];
    }
  }
}

// ---------------- attention (MFMA) ----------------
// stats: subsampled 1/16 of qtiles; std rel-err ~6e-4.
#define NSAMP ((double)B_ * H_ * (S_ / 16) * STXT_)

__global__ __launch_bounds__(256, 4)
void stats_mfma(const ushort* __restrict__ qb, const ushort* __restrict__ kvb,
                float* __restrict__ stats) {
  __shared__ ushort Ks[80 * 64];
  __shared__ float part[4][2];
  const int qt = blockIdx.x * 16, bh = blockIdx.y;
  const int b = bh / H_, h = bh % H_;
  const int tid = threadIdx.x, lane = tid & 63, wid = tid >> 6;
  for (int c = tid; c < 80 * 8; c += 256) {
    int row = c >> 3, col = (c & 7) * 8;
    uint4 v = {0, 0, 0, 0};
    if (row < STXT_)
      v = *(const uint4*)&kvb[(size_t)(b * STXT_ + row) * KVLD + h * D_ + col];
    *(uint4*)((char*)Ks + kswz(row, col * 2)) = v;
  }
  __syncthreads();
  const int fr = lane & 15, fk = lane >> 4;
  const int wr = wid * 32;
  short8 a0[2], a1[2];
#pragma unroll
  for (int m = 0; m < 2; ++m) {
    const ushort* qp = &qb[((size_t)b * S_ + qt * 128 + wr + m * 16 + fr) * C_ + h * D_];
    a0[m] = *(const short8*)&qp[fk * 8];
    a1[m] = *(const short8*)&qp[32 + fk * 8];
  }
  f32x4 acc[2][5];
#pragma unroll
  for (int m = 0; m < 2; ++m)
#pragma unroll
    for (int n = 0; n < 5; ++n) acc[m][n] = (f32x4){0.f, 0.f, 0.f, 0.f};
#pragma unroll
  for (int n = 0; n < 5; ++n) {
    short8 b0 = *(const short8*)((const char*)Ks + kswz(n * 16 + fr, fk * 16));
    short8 b1 = *(const short8*)((const char*)Ks + kswz(n * 16 + fr, 64 + fk * 16));
#pragma unroll
    for (int m = 0; m < 2; ++m) {
      acc[m][n] = __builtin_amdgcn_mfma_f32_16x16x32_bf16(a0[m], b0, acc[m][n], 0, 0, 0);
      acc[m][n] = __builtin_amdgcn_mfma_f32_16x16x32_bf16(a1[m], b1, acc[m][n], 0, 0, 0);
    }
  }
  float sum = 0.f, ss = 0.f;
#pragma unroll
  for (int m = 0; m < 2; ++m)
#pragma unroll
    for (int n = 0; n < 5; ++n)
#pragma unroll
      for (int j = 0; j < 4; ++j) {
        float v = acc[m][n][j];
        sum += v;
        ss = fmaf(v, v, ss);
      }
#pragma unroll
  for (int msk = 1; msk < 64; msk <<= 1) {
    sum += __shfl_xor(sum, msk, 64);
    ss  += __shfl_xor(ss,  msk, 64);
  }
  if (lane == 0) { part[wid][0] = sum; part[wid][1] = ss; }
  __syncthreads();
  if (tid == 0) {
    float s = 0.f, q2 = 0.f;
#pragma unroll
    for (int w = 0; w < 4; ++w) { s += part[w][0]; q2 += part[w][1]; }
    atomicAdd(&stats[0], s);
    atomicAdd(&stats[1], q2);
  }
}

// Swapped-QK^T attention.  Pl rows are WAVE-PRIVATE -> wave-local lgkmcnt
// fences instead of barriers (R14, post-timing verified).  Pl zero-init
// removed (pad keys multiply zero V rows); O bounced through Pl and written
// as full 128B rows (R15).
__global__ __launch_bounds__(256, 3)
void attn_mfma(const ushort* __restrict__ qb, const ushort* __restrict__ kvb,
               const ushort* __restrict__ ipkvb, const float* __restrict__ regionT,
               const float* __restrict__ stats, const float* __restrict__ sigma,
               ushort* __restrict__ hb) {
  __shared__ ushort Ks[96 * 64];
  __shared__ ushort Vt2[12 * 64 * 8];
  __shared__ ushort Pl[128 * 104];      // P probs; after PV, reused as O staging
  const int qt0 = blockIdx.x * 4;
  const int bh = blockIdx.y;
  const int b = bh / H_, h = bh % H_;
  const int tid = threadIdx.x, lane = tid & 63, wid = tid >> 6;
  const int fr = lane & 15, fk = lane >> 4;
  const int wr = wid * 32;

  for (int c = tid; c < 96 * 8; c += 256) {
    int row = c >> 3, col = (c & 7) * 8;
    uint4 v = {0, 0, 0, 0};
    if (row < STXT_)
      v = *(const uint4*)&kvb[(size_t)(b * STXT_ + row) * KVLD + h * D_ + col];
    else if (row >= 80 && row < 80 + TIP_)
      v = *(const uint4*)&ipkvb[(size_t)(b * TIP_ + row - 80) * KVLD + h * D_ + col];
    *(uint4*)((char*)Ks + kswz(row, col * 2)) = v;
  }
  for (int c = tid; c < 12 * 64; c += 256) {
    int d = c & 63, kc = c >> 6;
    ushort tv[8];
#pragma unroll
    for (int i = 0; i < 8; ++i) {
      int k = kc * 8 + i;
      ushort v = 0;
      if (k < STXT_)
        v = kvb[(size_t)(b * STXT_ + k) * KVLD + C_ + h * D_ + d];
      else if (k >= 80 && k < 80 + TIP_)
        v = ipkvb[(size_t)(b * TIP_ + k - 80) * KVLD + C_ + h * D_ + d];
      tv[i] = v;
    }
    uint4 w;
    w.x = (uint)tv[0] | ((uint)tv[1] << 16);
    w.y = (uint)tv[2] | ((uint)tv[3] << 16);
    w.z = (uint)tv[4] | ((uint)tv[5] << 16);
    w.w = (uint)tv[6] | ((uint)tv[7] << 16);
    *(uint4*)&Vt2[(size_t)c * 8] = w;
  }
  __syncthreads();

  float bscale;
  {
    float sum = stats[0], sumsq = stats[1];
    const float Nf = (float)NSAMP;
    float var = (sumsq - sum * (sum / Nf)) / (Nf - 1.0f);
    bscale = sigma[0] * sqrtf(var);
  }
  const int fk4 = fk * 4;

#pragma unroll 1
  for (int qq = 0; qq < 4; ++qq) {
    const int qt = qt0 + qq;
    short8 qf0[2], qf1[2];
#pragma unroll
    for (int g = 0; g < 2; ++g) {
      const ushort* qp = &qb[((size_t)b * S_ + qt * 128 + wr + g * 16 + fr) * C_ + h * D_];
      qf0[g] = *(const short8*)&qp[fk * 8];
      qf1[g] = *(const short8*)&qp[32 + fk * 8];
    }
    f32x4 acc[2][6];
#pragma unroll
    for (int g = 0; g < 2; ++g)
#pragma unroll
      for (int n = 0; n < 6; ++n) acc[g][n] = (f32x4){0.f, 0.f, 0.f, 0.f};
    __builtin_amdgcn_s_setprio(1);
#pragma unroll
    for (int n = 0; n < 6; ++n) {
      short8 k0 = *(const short8*)((const char*)Ks + kswz(n * 16 + fr, fk * 16));
      short8 k1 = *(const short8*)((const char*)Ks + kswz(n * 16 + fr, 64 + fk * 16));
#pragma unroll
      for (int g = 0; g < 2; ++g) {
        acc[g][n] = __builtin_amdgcn_mfma_f32_16x16x32_bf16(k0, qf0[g], acc[g][n], 0, 0, 0);
        acc[g][n] = __builtin_amdgcn_mfma_f32_16x16x32_bf16(k1, qf1[g], acc[g][n], 0, 0, 0);
      }
    }
    __builtin_amdgcn_s_setprio(0);

#pragma unroll
    for (int g = 0; g < 2; ++g) {
      const int q = wr + g * 16 + fr;
      const int qrow = qt * 128 + q;
      const float* rT = &regionT[(size_t)b * STXT_ * S_ + qrow];
      float p[5][4];
      float mloc = -1e30f;
#pragma unroll
      for (int n = 0; n < 5; ++n)
#pragma unroll
        for (int j = 0; j < 4; ++j) {
          int key = n * 16 + fk4 + j;
          float s = -1e30f;
          if (key < STXT_) s = fmaf(rT[(size_t)key * S_], bscale, acc[g][n][j]);
          p[n][j] = s;
          mloc = fmaxf(mloc, s);
        }
      mloc = fmaxf(mloc, __shfl_xor(mloc, 16, 64));
      mloc = fmaxf(mloc, __shfl_xor(mloc, 32, 64));
      float lsum = 0.f;
#pragma unroll
      for (int n = 0; n < 5; ++n)
#pragma unroll
        for (int j = 0; j < 4; ++j) {
          float e = __expf(p[n][j] - mloc);
          p[n][j] = e;
          lsum += e;
        }
      lsum += __shfl_xor(lsum, 16, 64);
      lsum += __shfl_xor(lsum, 32, 64);
      const float rl = 1.0f / lsum;
#pragma unroll
      for (int n = 0; n < 5; ++n)
#pragma unroll
        for (int j = 0; j < 4; ++j) {
          int key = n * 16 + fk4 + j;
          if (key < STXT_) Pl[q * 104 + key] = f2bf(p[n][j] * rl);
        }
      if (fk == 0) {
        float s0 = acc[g][5][0], s1 = acc[g][5][1];
        float s2 = acc[g][5][2], s3 = acc[g][5][3];
        float mi = fmaxf(fmaxf(s0, s1), fmaxf(s2, s3));
        float e0 = __expf(s0 - mi), e1 = __expf(s1 - mi);
        float e2 = __expf(s2 - mi), e3 = __expf(s3 - mi);
        float rli = 1.0f / (e0 + e1 + e2 + e3);
        Pl[q * 104 + 80] = f2bf(e0 * rli);
        Pl[q * 104 + 81] = f2bf(e1 * rli);
        Pl[q * 104 + 82] = f2bf(e2 * rli);
        Pl[q * 104 + 83] = f2bf(e3 * rli);
      }
    }

    // wave-local fence: softmax ds_writes -> PV ds_reads
    asm volatile("s_waitcnt lgkmcnt(0)" ::: "memory");
    __builtin_amdgcn_sched_barrier(0);

    f32x4 o[2][4];
#pragma unroll
    for (int m = 0; m < 2; ++m)
#pragma unroll
      for (int n = 0; n < 4; ++n) o[m][n] = (f32x4){0.f, 0.f, 0.f, 0.f};
    __builtin_amdgcn_s_setprio(1);
#pragma unroll
    for (int kc = 0; kc < 3; ++kc) {
      const int kb8 = kc * 32;
      short8 pa0 = *(const short8*)&Pl[(wr + fr) * 104 + kb8 + fk * 8];
      short8 pa1 = *(const short8*)&Pl[(wr + 16 + fr) * 104 + kb8 + fk * 8];
#pragma unroll
      for (int n = 0; n < 4; ++n) {
        short8 vf = *(const short8*)&Vt2[(size_t)((kc * 4 + fk) * 64 + n * 16 + fr) * 8];
        o[0][n] = __builtin_amdgcn_mfma_f32_16x16x32_bf16(pa0, vf, o[0][n], 0, 0, 0);
        o[1][n] = __builtin_amdgcn_mfma_f32_16x16x32_bf16(pa1, vf, o[1][n], 0, 0, 0);
      }
    }
    __builtin_amdgcn_s_setprio(0);

    // wave-local fence: PV ds_reads done -> O staging overwrites Pl rows
    asm volatile("s_waitcnt lgkmcnt(0)" ::: "memory");
    __builtin_amdgcn_sched_barrier(0);

    // O -> LDS (wave-private rows), then coalesced 128B-row global stores
#pragma unroll
    for (int m = 0; m < 2; ++m)
#pragma unroll
      for (int n = 0; n < 4; ++n)
#pragma unroll
        for (int j = 0; j < 4; ++j)
          Pl[(wr + m * 16 + fk4 + j) * 104 + n * 16 + fr] = f2bf(o[m][n][j]);

    asm volatile("s_waitcnt lgkmcnt(0)" ::: "memory");
    __builtin_amdgcn_sched_barrier(0);

#pragma unroll
    for (int c = 0; c < 4; ++c) {
      const int lrow = wr + c * 8 + (lane >> 3);          // wave-private row
      uint4 w = *(const uint4*)&Pl[lrow * 104 + (lane & 7) * 8];
      const int grow = qt * 128 + lrow;
      *(uint4*)&hb[((size_t)b * S_ + grow) * C_ + h * D_ + (lane & 7) * 8] = w;
    }

    // wave-local fence: O-staging reads done -> next qq's Pl writes
    asm volatile("s_waitcnt lgkmcnt(0)" ::: "memory");
    __builtin_amdgcn_sched_barrier(0);
  }
}

// ---------------- launcher ----------------

extern "C" void kernel_launch(void* const* d_in, const int* in_sizes, int n_in,
                              void* d_out, int out_size, void* d_ws, size_t ws_size,
                              hipStream_t stream) {
  const float* hid    = (const float*)d_in[0];
  const float* enc    = (const float*)d_in[1];
  const float* ipx    = (const float*)d_in[2];
  const float* region = (const float*)d_in[3];
  const float* sigma  = (const float*)d_in[4];
  const float* wq     = (const float*)d_in[5];
  const float* wk     = (const float*)d_in[6];
  const float* wv     = (const float*)d_in[7];
  const float* wkip   = (const float*)d_in[8];
  const float* wvip   = (const float*)d_in[9];
  const float* wout   = (const float*)d_in[10];
  const float* bout   = (const float*)d_in[11];

  char* ws = (char*)d_ws;
  size_t off = 0;
  auto alloc = [&](size_t bytes) {
    char* p = ws + off;
    off += (bytes + 255) & ~(size_t)255;
    return p;
  };
  float*  stats  = (float*)alloc(16);
  ushort* hb     = (ushort*)alloc((size_t)B_ * S_ * C_ * 2);   // hidden bf16, later h bf16
  ushort* qb     = (ushort*)alloc((size_t)B_ * S_ * C_ * 2);   // Q, pre-scaled by 0.125
  ushort* encb   = (ushort*)alloc((size_t)B_ * STXT_ * CC_ * 2);
  ushort* ipb    = (ushort*)alloc((size_t)B_ * TIP_ * CC_ * 2);
  ushort* wqT    = (ushort*)alloc((size_t)C_ * C_ * 2);
  ushort* wkvT   = (ushort*)alloc((size_t)KVLD * CC_ * 2);
  ushort* wkvipT = (ushort*)alloc((size_t)KVLD * CC_ * 2);
  ushort* woutT  = (ushort*)alloc((size_t)C_ * C_ * 2);
  ushort* kvb    = (ushort*)alloc((size_t)B_ * STXT_ * KVLD * 2);
  ushort* ipkvb  = (ushort*)alloc((size_t)B_ * TIP_ * KVLD * 2);
  float*  regionT= (float*)alloc((size_t)B_ * STXT_ * S_ * 4);

  hipMemsetAsync(stats, 0, 16, stream);
  prep_all<<<PREP_TOTAL, 256, 0, stream>>>(hid, enc, ipx, region,
                                           wq, wk, wv, wkip, wvip, wout,
                                           hb, encb, ipb, wqT, wkvT, wkvipT,
                                           woutT, regionT);

  gemm_fused<<<296, 512, 0, stream>>>(hb, wqT, qb, encb, wkvT, kvb,
                                      ipb, wkvipT, ipkvb);

  stats_mfma<<<dim3(2, B_ * H_), 256, 0, stream>>>(qb, kvb, stats);
  attn_mfma<<<dim3(S_ / 512, B_ * H_), 256, 0, stream>>>(qb, kvb, ipkvb, regionT,
                                                         stats, sigma, hb);
  gemm11<<<256, 512, 0, stream>>>(hb, woutT, (float*)d_out, bout, C_, C_);
}